// Round 1
// baseline (183.270 us; speedup 1.0000x reference)
//
#include <hip/hip_runtime.h>
#include <math.h>

#define DIMX 128
#define HIDX 256
#define NBX 2048
#define NTOTX 32768
#define NMAXX 32
#define VMID 192
#define SMID 128
#define DMID 192
#define KTAB 256

#define EROWS 32
#define XPITCH (EROWS + 2)   // 34: keeps float2 alignment, breaks 32-bank stride

__device__ __forceinline__ float mishf(float v) {
    float sp = (v > 20.0f) ? v : log1pf(expf(v));
    return v * tanhf(sp);
}

// cos/sin table for keys: angle computed exactly as reference: (t_j * k) * 8
__global__ void k_tab(float* __restrict__ ct, float* __restrict__ st) {
    int k = blockIdx.x, j = threadIdx.x;
    float t = (float)j * (1.0f / 255.0f);
    float th = (t * (float)k) * 8.0f;
    float s, c;
    sincosf(th, &s, &c);
    ct[k * HIDX + j] = c;
    st[k * HIDX + j] = s;
}

// mag = x @ rank_w + rank_b ; one wave per row
__global__ void k_mag(const float* __restrict__ x, const float* __restrict__ rw,
                      const float* __restrict__ rb, float* __restrict__ mag) {
    int gid = blockIdx.x * blockDim.x + threadIdx.x;
    int row = gid >> 6, lane = gid & 63;
    if (row >= NTOTX) return;
    const float* xr = x + (size_t)row * DIMX;
    float s = xr[lane] * rw[lane] + xr[lane + 64] * rw[lane + 64];
#pragma unroll
    for (int off = 32; off; off >>= 1) s += __shfl_down(s, off, 64);
    if (lane == 0) mag[row] = s + rb[0];
}

// segment boundaries by binary search over sorted batch
__global__ void k_seg(const int* __restrict__ batch, int* __restrict__ segs,
                      int* __restrict__ segn) {
    int b = blockIdx.x * blockDim.x + threadIdx.x;
    if (b >= NBX) return;
    int lo = 0, hi = NTOTX;
    while (lo < hi) { int m = (lo + hi) >> 1; if (batch[m] < b) lo = m + 1; else hi = m; }
    int st = lo;
    hi = NTOTX;
    while (lo < hi) { int m = (lo + hi) >> 1; if (batch[m] <= b) lo = m + 1; else hi = m; }
    segs[b] = st; segn[b] = lo - st;
}

// stable rank within segment (== lexsort(batch primary, mag secondary)); emits order[]
__global__ void k_rank(const int* __restrict__ batch, const float* __restrict__ mag,
                       const int* __restrict__ segs, const int* __restrict__ segn,
                       int* __restrict__ order) {
    int i = blockIdx.x * blockDim.x + threadIdx.x;
    if (i >= NTOTX) return;
    int b = batch[i];
    int s = segs[b], e = s + segn[b];
    float mi = mag[i];
    int r = 0;
    for (int j = s; j < e; j++) {
        float mj = mag[j];
        r += (mj < mi) || (mj == mi && j < i);
    }
    order[s + r] = i;
}

// fused encoder: h = mish(LN(x@w1+b1))@w2 + b2, 32 rows per block
__global__ __launch_bounds__(256) void k_enc(const float* __restrict__ x,
    const float* __restrict__ w1, const float* __restrict__ b1,
    const float* __restrict__ g1, const float* __restrict__ be1,
    const float* __restrict__ w2, const float* __restrict__ b2,
    float* __restrict__ h) {
    __shared__ __align__(16) float xT[DIMX * XPITCH];   // x transposed  [k][r]
    __shared__ __align__(16) float aT[VMID * XPITCH];   // act transposed [k][r]
    int tid = threadIdx.x;
    int rowbase = blockIdx.x * EROWS;
    for (int idx = tid; idx < EROWS * DIMX; idx += 256) {
        int r = idx >> 7, k = idx & 127;
        xT[k * XPITCH + r] = x[(size_t)(rowbase + r) * DIMX + k];
    }
    __syncthreads();
    int c = tid & 63;        // output col base
    int rg = tid >> 6;       // row group: 8 rows
    int r0 = rg * 8;

    // GEMM1: acc[3 cols][8 rows]
    float acc[3][8];
#pragma unroll
    for (int j = 0; j < 3; j++)
#pragma unroll
        for (int i = 0; i < 8; i++) acc[j][i] = 0.0f;
    for (int k = 0; k < DIMX; k++) {
        float wa = w1[k * VMID + c];
        float wb = w1[k * VMID + c + 64];
        float wc = w1[k * VMID + c + 128];
        const float* xp = &xT[k * XPITCH + r0];
        float xv[8];
#pragma unroll
        for (int q = 0; q < 4; q++) {
            float2 t2 = *(const float2*)(xp + 2 * q);
            xv[2 * q] = t2.x; xv[2 * q + 1] = t2.y;
        }
#pragma unroll
        for (int i = 0; i < 8; i++) {
            acc[0][i] += wa * xv[i];
            acc[1][i] += wb * xv[i];
            acc[2][i] += wc * xv[i];
        }
    }
    // LayerNorm (two-pass var, matches jnp.var) + mish; write transposed acts
#pragma unroll
    for (int i = 0; i < 8; i++) {
        float v0 = acc[0][i] + b1[c];
        float v1 = acc[1][i] + b1[c + 64];
        float v2 = acc[2][i] + b1[c + 128];
        float s = v0 + v1 + v2;
#pragma unroll
        for (int off = 32; off; off >>= 1) s += __shfl_xor(s, off, 64);
        float mean = s / 192.0f;
        float d0 = v0 - mean, d1 = v1 - mean, d2 = v2 - mean;
        float q = d0 * d0 + d1 * d1 + d2 * d2;
#pragma unroll
        for (int off = 32; off; off >>= 1) q += __shfl_xor(q, off, 64);
        float inv = 1.0f / sqrtf(q / 192.0f + 1e-5f);
        aT[(c)*XPITCH + r0 + i]       = mishf(d0 * inv * g1[c] + be1[c]);
        aT[(c + 64) * XPITCH + r0 + i]  = mishf(d1 * inv * g1[c + 64] + be1[c + 64]);
        aT[(c + 128) * XPITCH + r0 + i] = mishf(d2 * inv * g1[c + 128] + be1[c + 128]);
    }
    __syncthreads();

    // GEMM2: acc2[4 cols][8 rows]
    float acc2[4][8];
#pragma unroll
    for (int j = 0; j < 4; j++)
#pragma unroll
        for (int i = 0; i < 8; i++) acc2[j][i] = 0.0f;
    for (int k = 0; k < VMID; k++) {
        float w[4];
#pragma unroll
        for (int j = 0; j < 4; j++) w[j] = w2[k * HIDX + c + 64 * j];
        const float* ap = &aT[k * XPITCH + r0];
        float av[8];
#pragma unroll
        for (int q = 0; q < 4; q++) {
            float2 t2 = *(const float2*)(ap + 2 * q);
            av[2 * q] = t2.x; av[2 * q + 1] = t2.y;
        }
#pragma unroll
        for (int i = 0; i < 8; i++)
#pragma unroll
            for (int j = 0; j < 4; j++)
                acc2[j][i] += w[j] * av[i];
    }
#pragma unroll
    for (int i = 0; i < 8; i++) {
        size_t row = (size_t)(rowbase + r0 + i);
#pragma unroll
        for (int j = 0; j < 4; j++)
            h[row * HIDX + c + 64 * j] = acc2[j][i] + b2[c + 64 * j];
    }
}

// z = sum_seg h*keys (in sorted order, matching ref accumulation) + n*card_w + card_b
__global__ __launch_bounds__(256) void k_z(const float* __restrict__ h,
    const int* __restrict__ order, const int* __restrict__ segs, const int* __restrict__ segn,
    const float* __restrict__ ct, const float* __restrict__ st,
    const float* __restrict__ cw, const float* __restrict__ cb,
    float* __restrict__ zre, float* __restrict__ zim) {
    int b = blockIdx.x, j = threadIdx.x;
    int s = segs[b], n = segn[b];
    float zr = 0.f, zi = 0.f;
    for (int p = 0; p < n; p++) {
        int e = order[s + p];
        float hv = h[(size_t)e * HIDX + j];
        float cv, sv;
        if (p < KTAB) { cv = ct[p * HIDX + j]; sv = st[p * HIDX + j]; }
        else {
            float t = (float)j * (1.0f / 255.0f);
            float th = (t * (float)p) * 8.0f;
            sincosf(th, &sv, &cv);
        }
        zr += hv * cv; zi += hv * sv;
    }
    float nf = (float)n;
    zre[(size_t)b * HIDX + j] = zr + nf * cw[j] + cb[j];
    zim[(size_t)b * HIDX + j] = zi;
}

// size MLP -> n_pred, mask, zc
__global__ __launch_bounds__(128) void k_size(const float* __restrict__ zre,
    const float* __restrict__ w1, const float* __restrict__ b1,
    const float* __restrict__ g, const float* __restrict__ be,
    const float* __restrict__ w2, const float* __restrict__ b2s,
    const float* __restrict__ cw, const float* __restrict__ cb,
    float* __restrict__ zcre, float* __restrict__ npredf, int* __restrict__ npredi,
    float* __restrict__ out_mask, float* __restrict__ out_np) {
    __shared__ float zrow[HIDX];
    __shared__ float red0[2], red1[2], red2[2];
    int b = blockIdx.x, tid = threadIdx.x;
    const float* zp = zre + (size_t)b * HIDX;
    zrow[tid] = zp[tid];
    zrow[tid + 128] = zp[tid + 128];
    __syncthreads();
    float v = b1[tid];
    for (int k = 0; k < HIDX; k++) v += zrow[k] * w1[k * SMID + tid];
    int wv = tid >> 6;
    float s = v;
#pragma unroll
    for (int off = 32; off; off >>= 1) s += __shfl_xor(s, off, 64);
    if ((tid & 63) == 0) red0[wv] = s;
    __syncthreads();
    float mean = (red0[0] + red0[1]) / 128.0f;
    float d = v - mean;
    float q = d * d;
#pragma unroll
    for (int off = 32; off; off >>= 1) q += __shfl_xor(q, off, 64);
    if ((tid & 63) == 0) red1[wv] = q;
    __syncthreads();
    float var = (red1[0] + red1[1]) / 128.0f;
    float lv = d * (1.0f / sqrtf(var + 1e-5f)) * g[tid] + be[tid];
    float a = mishf(lv);
    float p = a * w2[tid];
#pragma unroll
    for (int off = 32; off; off >>= 1) p += __shfl_xor(p, off, 64);
    if ((tid & 63) == 0) red2[wv] = p;
    __syncthreads();
    float h2 = red2[0] + red2[1] + b2s[0];
    float npf = fmaxf(rintf(h2), 0.0f);       // rintf == round-half-even == jnp.round
    int npi = min((int)npf, NMAXX);
    for (int jj = tid; jj < HIDX; jj += 128)
        zcre[(size_t)b * HIDX + jj] = zrow[jj] - (npf * cw[jj] + cb[jj]);
    if (tid < NMAXX) out_mask[b * NMAXX + tid] = (tid < npi) ? 1.0f : 0.0f;
    if (tid == 0) { npredf[b] = npf; npredi[b] = npi; out_np[b] = (float)npi; }
}

__global__ void k_zero(float4* __restrict__ p, int n4) {
    int i = blockIdx.x * blockDim.x + threadIdx.x;
    int stride = gridDim.x * blockDim.x;
    for (; i < n4; i += stride) p[i] = make_float4(0.f, 0.f, 0.f, 0.f);
}

// decoder: only rows m < n_pred_i[b]
__global__ __launch_bounds__(256) void k_dec(const float* __restrict__ zcre,
    const float* __restrict__ zim, const int* __restrict__ npredi,
    const float* __restrict__ ct, const float* __restrict__ st,
    const float* __restrict__ w1, const float* __restrict__ b1,
    const float* __restrict__ w2, const float* __restrict__ b2,
    float* __restrict__ xr) {
    int m = blockIdx.x, b = blockIdx.y;
    if (m >= npredi[b]) return;
    __shared__ float zp[HIDX];
    __shared__ float a[DMID];
    int tid = threadIdx.x;
    {
        float cv = ct[m * HIDX + tid], sv = st[m * HIDX + tid];
        zp[tid] = zcre[(size_t)b * HIDX + tid] * cv - zim[(size_t)b * HIDX + tid] * sv;
    }
    __syncthreads();
    if (tid < DMID) {
        float v = b1[tid];
        for (int k = 0; k < HIDX; k++) v += zp[k] * w1[k * DMID + tid];
        a[tid] = mishf(v);
    }
    __syncthreads();
    if (tid < DIMX) {
        float v = b2[tid];
        for (int k = 0; k < DMID; k++) v += a[k] * w2[k * DIMX + tid];
        xr[((size_t)b * NMAXX + m) * DIMX + tid] = v;
    }
}

extern "C" void kernel_launch(void* const* d_in, const int* in_sizes, int n_in,
                              void* d_out, int out_size, void* d_ws, size_t ws_size,
                              hipStream_t stream) {
    const float* x      = (const float*)d_in[0];
    const int*   batch  = (const int*)d_in[1];
    const float* rank_w = (const float*)d_in[2];
    const float* rank_b = (const float*)d_in[3];
    const float* vw1    = (const float*)d_in[4];
    const float* vb1    = (const float*)d_in[5];
    const float* vlg    = (const float*)d_in[6];
    const float* vlb    = (const float*)d_in[7];
    const float* vw2    = (const float*)d_in[8];
    const float* vb2    = (const float*)d_in[9];
    const float* cw     = (const float*)d_in[10];
    const float* cb     = (const float*)d_in[11];
    const float* sw1    = (const float*)d_in[12];
    const float* sb1    = (const float*)d_in[13];
    const float* slg    = (const float*)d_in[14];
    const float* slb    = (const float*)d_in[15];
    const float* sw2    = (const float*)d_in[16];
    const float* sb2    = (const float*)d_in[17];
    const float* dw1    = (const float*)d_in[18];
    const float* db1    = (const float*)d_in[19];
    const float* dw2    = (const float*)d_in[20];
    const float* db2    = (const float*)d_in[21];

    char* ws = (char*)d_ws;
    size_t off = 0;
    auto alloc = [&](size_t bytes) {
        void* p = ws + off;
        off += (bytes + 255) & ~(size_t)255;
        return p;
    };
    float* mag   = (float*)alloc((size_t)NTOTX * 4);
    int*   segs  = (int*)alloc((size_t)NBX * 4);
    int*   segn  = (int*)alloc((size_t)NBX * 4);
    int*   order = (int*)alloc((size_t)NTOTX * 4);
    float* ct    = (float*)alloc((size_t)KTAB * HIDX * 4);
    float* st    = (float*)alloc((size_t)KTAB * HIDX * 4);
    float* zre   = (float*)alloc((size_t)NBX * HIDX * 4);
    float* zim   = (float*)alloc((size_t)NBX * HIDX * 4);
    float* zcre  = (float*)alloc((size_t)NBX * HIDX * 4);
    float* npf   = (float*)alloc((size_t)NBX * 4);
    int*   npi   = (int*)alloc((size_t)NBX * 4);
    float* h     = (float*)alloc((size_t)NTOTX * HIDX * 4);

    float* out_xr   = (float*)d_out;
    float* out_mask = out_xr + (size_t)NBX * NMAXX * DIMX;
    float* out_np   = out_mask + (size_t)NBX * NMAXX;

    hipLaunchKernelGGL(k_tab,  dim3(KTAB), dim3(HIDX), 0, stream, ct, st);
    hipLaunchKernelGGL(k_mag,  dim3(NTOTX / 4), dim3(256), 0, stream, x, rank_w, rank_b, mag);
    hipLaunchKernelGGL(k_seg,  dim3(NBX / 256), dim3(256), 0, stream, batch, segs, segn);
    hipLaunchKernelGGL(k_rank, dim3(NTOTX / 256), dim3(256), 0, stream, batch, mag, segs, segn, order);
    hipLaunchKernelGGL(k_enc,  dim3(NTOTX / EROWS), dim3(256), 0, stream,
                       x, vw1, vb1, vlg, vlb, vw2, vb2, h);
    hipLaunchKernelGGL(k_z,    dim3(NBX), dim3(HIDX), 0, stream,
                       h, order, segs, segn, ct, st, cw, cb, zre, zim);
    hipLaunchKernelGGL(k_size, dim3(NBX), dim3(SMID), 0, stream,
                       zre, sw1, sb1, slg, slb, sw2, sb2, cw, cb,
                       zcre, npf, npi, out_mask, out_np);
    hipLaunchKernelGGL(k_zero, dim3(4096), dim3(256), 0, stream,
                       (float4*)out_xr, (int)((size_t)NBX * NMAXX * DIMX / 4));
    hipLaunchKernelGGL(k_dec,  dim3(NMAXX, NBX), dim3(256), 0, stream,
                       zcre, zim, npi, ct, st, dw1, db1, dw2, db2, out_xr);
    (void)in_sizes; (void)n_in; (void)out_size; (void)ws_size;
}